// Round 10
// baseline (77.693 us; speedup 1.0000x reference)
//
#include <hip/hip_runtime.h>
#include <math.h>

#define NCLS 1000
#define NF4  250     // float4s per row
#define TPB  256
#define WPB  4       // waves (rows) per block
#define NXCD 8

typedef float vfloat4 __attribute__((ext_vector_type(4)));  // NT-builtin-compatible

#if __has_builtin(__builtin_amdgcn_exp2f)
__device__ __forceinline__ float fast_exp2(float x) { return __builtin_amdgcn_exp2f(x); }
#else
__device__ __forceinline__ float fast_exp2(float x) { return exp2f(x); }
#endif

// ---------------------------------------------------------------------------
// cum[k-1] for the uniform row per jax.lax.associative_scan (tree) order.
// Verified bit-exact in R3-R9 (absmax == 0.0).
// ---------------------------------------------------------------------------
__device__ __forceinline__ float scan_val(int k) {
    const unsigned xb = __float_as_uint(0.001f);
    const int hb = 31 - __clz(k);
    float acc = __uint_as_float(xb + ((unsigned)hb << 23));  // x * 2^hb, exact
    #pragma unroll 1
    for (int l = hb - 1; l >= 0; --l) {
        if (k & (1u << l)) {
            const float t = __uint_as_float(xb + ((unsigned)l << 23)); // x*2^l
            acc += t;
            asm volatile("" : "+v"(acc));
        }
    }
    return acc;
}

// ---------------------------------------------------------------------------
// idx = #{k in [1,1000]: scan_val(k) < th}.  Only k0 = trunc(fma(th,1000,.5))
// is ambiguous (margin proof in R7); bit-identical to the full count.
// ---------------------------------------------------------------------------
__device__ __forceinline__ int count_below(float th) {
    int k0 = (int)fmaf(th, 1000.0f, 0.5f);
    k0 = (k0 < 1) ? 1 : (k0 > 1000 ? 1000 : k0);
    return (k0 - 1) + ((scan_val(k0) < th) ? 1 : 0);
}

// ---------------------------------------------------------------------------
// Wave-level (64-lane) reductions — pure register butterflies, no barriers.
// ---------------------------------------------------------------------------
__device__ __forceinline__ float wave_max(float v) {
    #pragma unroll
    for (int o = 32; o; o >>= 1) v = fmaxf(v, __shfl_xor(v, o));
    return v;
}
__device__ __forceinline__ float wave_sum(float v) {
    #pragma unroll
    for (int o = 32; o; o >>= 1) v += __shfl_xor(v, o);
    return v;
}
__device__ __forceinline__ int wave_sumi(int v) {
    #pragma unroll
    for (int o = 32; o; o >>= 1) v += __shfl_xor(v, o);
    return v;
}

// ---------------------------------------------------------------------------
// One WAVE per row; early NT store decoupled from the verification chain.
// XCD-aware contiguous-chunk block swizzle: adjacent rows on the same XCD
// (merges the 64-B lines shared by odd/even row pairs in one L2).
// ---------------------------------------------------------------------------
__global__ __launch_bounds__(TPB, 8) void defence_kernel(
    const float* __restrict__ logits,
    const float* __restrict__ noise,
    const float* __restrict__ u,
    float* __restrict__ out,
    int batch, int nblk)
{
    int bid = blockIdx.x;
    if ((nblk & (NXCD - 1)) == 0) {              // bijective when nblk % 8 == 0
        const int cpx = nblk / NXCD;
        bid = (bid & (NXCD - 1)) * cpx + (bid / NXCD);
    }
    const int lane = threadIdx.x & 63;
    const int wid  = threadIdx.x >> 6;
    const int row  = bid * WPB + wid;
    if (row >= batch) return;                    // wave-uniform

    __shared__ unsigned char kbuf[WPB][NCLS];    // cold path only

    const float uu = u[row];

    const float NEG = -INFINITY;
    const vfloat4* lg4 = reinterpret_cast<const vfloat4*>(logits + (size_t)row * NCLS);
    const vfloat4* nz4 = reinterpret_cast<const vfloat4*>(noise  + (size_t)row * NCLS);

    // issue ALL row loads up front, non-temporal (single-use streams)
    vfloat4 lv[4], nv[4];
    #pragma unroll
    for (int t = 0; t < 4; ++t) {
        const int j = lane + 64 * t;
        const bool a = j < NF4;
        if (a) {
            lv[t] = __builtin_nontemporal_load(&lg4[j]);
            nv[t] = __builtin_nontemporal_load(&nz4[j]);
        } else {
            lv[t] = (vfloat4){NEG, NEG, NEG, NEG};
            nv[t] = (vfloat4){0.f, 0.f, 0.f, 0.f};
        }
    }

    // ---- sampling index from u alone; NT-store output EARLY ----
    const float T999 = scan_val(1000);
    const float th0  = uu * T999;                // bit-identical th
    int idx = count_below(th0);

    const float V0 = logf(1e-7f);                // EPS/C
    const float V1 = logf(0.9999f + 1e-7f);      // (1-EPS) + EPS/C
    vfloat4* o4 = reinterpret_cast<vfloat4*>(out + (size_t)row * NCLS);
    #pragma unroll
    for (int t = 0; t < 4; ++t) {
        const int j = lane + 64 * t;
        if (j < NF4) {
            vfloat4 ov = {V0, V0, V0, V0};
            const int base = 4 * j;
            if (idx >= base && idx < base + 4)
                ov[idx - base] = V1;
            __builtin_nontemporal_store(ov, &o4[j]);
        }
    }

    // ---- fast-path verification: decide K==0 (margin ~2x) ----
    const float K6 = 0.2404491734814939f;        // log2(e)/6
    float mA = NEG, sA = 0.f;
    #pragma unroll
    for (int t = 0; t < 4; ++t) {
        mA = fmaxf(mA, fmaxf(fmaxf(lv[t][0], lv[t][1]), fmaxf(lv[t][2], lv[t][3])));
        sA += (fast_exp2(lv[t][0] * K6) + fast_exp2(lv[t][1] * K6))
            + (fast_exp2(lv[t][2] * K6) + fast_exp2(lv[t][3] * K6));
    }
    const float m1 = wave_max(mA);               // independent shfl chains
    const float s1 = wave_sum(sA);
    const float mc = fast_exp2(m1 * K6) / s1;    // max softmax#1 prob
    const float sd = fmaf(0.6f, mc * mc, 0.3f);

    const float L2E = 1.4426950408889634f;
    float m2l = NEG, s2l = 0.f;
    #pragma unroll
    for (int t = 0; t < 4; ++t) {
        const float y0 = fmaf(nv[t][0], sd, lv[t][0] * (1.0f / 6.0f));
        const float y1 = fmaf(nv[t][1], sd, lv[t][1] * (1.0f / 6.0f));
        const float y2 = fmaf(nv[t][2], sd, lv[t][2] * (1.0f / 6.0f));
        const float y3 = fmaf(nv[t][3], sd, lv[t][3] * (1.0f / 6.0f));
        m2l = fmaxf(m2l, fmaxf(fmaxf(y0, y1), fmaxf(y2, y3)));
        s2l += (fast_exp2(y0 * L2E) + fast_exp2(y1 * L2E))
             + (fast_exp2(y2 * L2E) + fast_exp2(y3 * L2E));
    }
    const float m2  = wave_max(m2l);
    const float s2  = wave_sum(s2l);
    const float e2m = fast_exp2(m2 * L2E);       // overflow/NaN -> exact path

    // K==0 <=> max renorm prob <= 0.05; require maxp < 1/22 = 0.0455.
    // Data margin: maxp <= ~0.026. Boundary rows fall to the exact path.
    if (__builtin_expect(!(s2 > 22.0f * e2m), 0)) {
        // ---- exact reference-semantics path (wave-uniform; cold) ----
        const float m1x = m1 / 6.0f;             // max(l)/6 == max(l/6)
        float se1 = 0.f;
        #pragma unroll
        for (int t = 0; t < 4; ++t)
            se1 += expf(lv[t][0] / 6.0f - m1x) + expf(lv[t][1] / 6.0f - m1x)
                 + expf(lv[t][2] / 6.0f - m1x) + expf(lv[t][3] / 6.0f - m1x);
        const float s1x = wave_sum(se1);
        const float mcx = 1.0f / s1x;
        const float sdx = 0.3f + 0.6f * (mcx * mcx);

        float m2xl = NEG;
        #pragma unroll
        for (int t = 0; t < 4; ++t) {
            const float y0 = lv[t][0] / 6.0f + nv[t][0] * sdx;
            const float y1 = lv[t][1] / 6.0f + nv[t][1] * sdx;
            const float y2 = lv[t][2] / 6.0f + nv[t][2] * sdx;
            const float y3 = lv[t][3] / 6.0f + nv[t][3] * sdx;
            m2xl = fmaxf(m2xl, fmaxf(fmaxf(y0, y1), fmaxf(y2, y3)));
        }
        const float m2x = wave_max(m2xl);
        float se2 = 0.f;
        #pragma unroll
        for (int t = 0; t < 4; ++t)
            se2 += expf(lv[t][0] / 6.0f + nv[t][0] * sdx - m2x)
                 + expf(lv[t][1] / 6.0f + nv[t][1] * sdx - m2x)
                 + expf(lv[t][2] / 6.0f + nv[t][2] * sdx - m2x)
                 + expf(lv[t][3] / 6.0f + nv[t][3] * sdx - m2x);
        const float s2x = wave_sum(se2);
        float cs = 0.f;
        #pragma unroll
        for (int t = 0; t < 4; ++t)
            cs += fminf(expf(lv[t][0] / 6.0f + nv[t][0] * sdx - m2x) / s2x, 0.6f)
                + fminf(expf(lv[t][1] / 6.0f + nv[t][1] * sdx - m2x) / s2x, 0.6f)
                + fminf(expf(lv[t][2] / 6.0f + nv[t][2] * sdx - m2x) / s2x, 0.6f)
                + fminf(expf(lv[t][3] / 6.0f + nv[t][3] * sdx - m2x) / s2x, 0.6f);
        const float rsum = wave_sum(cs);
        int kls = 0;
        #pragma unroll
        for (int t = 0; t < 4; ++t) {
            const int j = lane + 64 * t;
            if (j < NF4) {
                const float yv[4] = {
                    lv[t][0] / 6.0f + nv[t][0] * sdx, lv[t][1] / 6.0f + nv[t][1] * sdx,
                    lv[t][2] / 6.0f + nv[t][2] * sdx, lv[t][3] / 6.0f + nv[t][3] * sdx };
                #pragma unroll
                for (int c = 0; c < 4; ++c) {
                    const float cl = fminf(expf(yv[c] - m2x) / s2x, 0.6f);
                    const int kk = (int)rintf((cl / rsum) * 10.0f);
                    kbuf[wid][4 * j + c] = (unsigned char)kk;
                    kls += kk;
                }
            }
        }
        const int K = wave_sumi(kls);
        int idx2;
        if (K == 0) {
            idx2 = count_below(th0);
        } else {
            asm volatile("s_waitcnt lgkmcnt(0)" ::: "memory");
            __builtin_amdgcn_wave_barrier();
            int cnt = 0;
            if (lane == 0) {
                const double tab[11] = {0.0, 0.1, 0.2, 0.3, 0.4, 0.5,
                                        0.6, 0.7, 0.8, 0.9, 1.0};
                double c = 0.0;
                for (int i = 0; i < NCLS; ++i) c += tab[kbuf[wid][i]];
                const double th = (double)uu * c;
                c = 0.0;
                for (int i = 0; i < NCLS; ++i) {
                    c += tab[kbuf[wid][i]];
                    cnt += (c < th) ? 1 : 0;
                }
            }
            idx2 = __shfl(cnt, 0);
        }
        // rewrite the row with the exact index
        #pragma unroll
        for (int t = 0; t < 4; ++t) {
            const int j = lane + 64 * t;
            if (j < NF4) {
                vfloat4 ov = {V0, V0, V0, V0};
                const int base = 4 * j;
                if (idx2 >= base && idx2 < base + 4)
                    ov[idx2 - base] = V1;
                __builtin_nontemporal_store(ov, &o4[j]);
            }
        }
    }
}

extern "C" void kernel_launch(void* const* d_in, const int* in_sizes, int n_in,
                              void* d_out, int out_size, void* d_ws, size_t ws_size,
                              hipStream_t stream) {
    const float* logits = (const float*)d_in[0];
    const float* noise  = (const float*)d_in[1];
    const float* u      = (const float*)d_in[2];
    float* out = (float*)d_out;

    const int batch = in_sizes[2];       // 32768 rows (u is [B,1])
    const int blocks = (batch + WPB - 1) / WPB;

    hipLaunchKernelGGL(defence_kernel, dim3(blocks), dim3(TPB), 0, stream,
                       logits, noise, u, out, batch, blocks);
}

// Round 11
// 66.172 us; speedup vs baseline: 1.1741x; 1.1741x over previous
//
#include <hip/hip_runtime.h>
#include <math.h>

#define NCLS 1000
#define NF4  250     // float4s per row
#define TPB  256
#define WPB  4       // waves (rows) per block

typedef float vfloat4 __attribute__((ext_vector_type(4)));

#if __has_builtin(__builtin_amdgcn_exp2f)
__device__ __forceinline__ float fast_exp2(float x) { return __builtin_amdgcn_exp2f(x); }
#else
__device__ __forceinline__ float fast_exp2(float x) { return exp2f(x); }
#endif

// ---------------------------------------------------------------------------
// cum[k-1] for the uniform row per jax.lax.associative_scan (tree) order.
// Verified bit-exact in R3-R10 (absmax == 0.0).
// ---------------------------------------------------------------------------
__device__ __forceinline__ float scan_val(int k) {
    const unsigned xb = __float_as_uint(0.001f);
    const int hb = 31 - __clz(k);
    float acc = __uint_as_float(xb + ((unsigned)hb << 23));  // x * 2^hb, exact
    #pragma unroll 1
    for (int l = hb - 1; l >= 0; --l) {
        if (k & (1u << l)) {
            const float t = __uint_as_float(xb + ((unsigned)l << 23)); // x*2^l
            acc += t;
            asm volatile("" : "+v"(acc));
        }
    }
    return acc;
}

// idx = #{k in [1,1000]: scan_val(k) < th}; only k0 = trunc(fma(th,1000,.5))
// is ambiguous (margin proof in R7); bit-identical to the full count.
__device__ __forceinline__ int count_below(float th) {
    int k0 = (int)fmaf(th, 1000.0f, 0.5f);
    k0 = (k0 < 1) ? 1 : (k0 > 1000 ? 1000 : k0);
    return (k0 - 1) + ((scan_val(k0) < th) ? 1 : 0);
}

__device__ __forceinline__ float wave_max(float v) {
    #pragma unroll
    for (int o = 32; o; o >>= 1) v = fmaxf(v, __shfl_xor(v, o));
    return v;
}
__device__ __forceinline__ float wave_sum(float v) {
    #pragma unroll
    for (int o = 32; o; o >>= 1) v += __shfl_xor(v, o);
    return v;
}
__device__ __forceinline__ int wave_sumi(int v) {
    #pragma unroll
    for (int o = 32; o; o >>= 1) v += __shfl_xor(v, o);
    return v;
}

// ---------------------------------------------------------------------------
// Kernel 1 — WRITER: pure write stream (output depends only on u).
// Plain stores: lines fill completely & evict whole -> ideal WRITE volume
// at the fillBuffer-measured ~6.8 TB/s path.
// ---------------------------------------------------------------------------
__global__ __launch_bounds__(TPB, 8) void writer_kernel(
    const float* __restrict__ u,
    float* __restrict__ out,
    int batch)
{
    const int lane = threadIdx.x & 63;
    const int wid  = threadIdx.x >> 6;
    const int row  = blockIdx.x * WPB + wid;
    if (row >= batch) return;                    // wave-uniform

    const float T999 = scan_val(1000);
    const float th0  = u[row] * T999;            // bit-identical th
    const int idx = count_below(th0);

    const float V0 = logf(1e-7f);                // EPS/C
    const float V1 = logf(0.9999f + 1e-7f);      // (1-EPS) + EPS/C
    vfloat4* o4 = reinterpret_cast<vfloat4*>(out + (size_t)row * NCLS);
    #pragma unroll
    for (int t = 0; t < 4; ++t) {
        const int j = lane + 64 * t;
        if (j < NF4) {
            vfloat4 ov = {V0, V0, V0, V0};
            const int base = 4 * j;
            if (idx >= base && idx < base + 4)
                ov[idx - base] = V1;
            o4[j] = ov;
        }
    }
}

// ---------------------------------------------------------------------------
// Kernel 2 — VERIFIER: pure read stream. Decides K==0 (margin ~2x); writes
// NOTHING on the fast path. Boundary rows -> exact reference semantics +
// row rewrite (ordered after writer by stream ordering).
// ---------------------------------------------------------------------------
__global__ __launch_bounds__(TPB, 8) void verify_kernel(
    const float* __restrict__ logits,
    const float* __restrict__ noise,
    const float* __restrict__ u,
    float* __restrict__ out,
    int batch)
{
    const int lane = threadIdx.x & 63;
    const int wid  = threadIdx.x >> 6;
    const int row  = blockIdx.x * WPB + wid;
    if (row >= batch) return;                    // wave-uniform

    __shared__ unsigned char kbuf[WPB][NCLS];    // cold path only

    const float NEG = -INFINITY;
    const vfloat4* lg4 = reinterpret_cast<const vfloat4*>(logits + (size_t)row * NCLS);
    const vfloat4* nz4 = reinterpret_cast<const vfloat4*>(noise  + (size_t)row * NCLS);

    // NT loads: single-use streams, preserve the stable L3-resident split
    vfloat4 lv[4], nv[4];
    #pragma unroll
    for (int t = 0; t < 4; ++t) {
        const int j = lane + 64 * t;
        if (j < NF4) {
            lv[t] = __builtin_nontemporal_load(&lg4[j]);
            nv[t] = __builtin_nontemporal_load(&nz4[j]);
        } else {
            lv[t] = (vfloat4){NEG, NEG, NEG, NEG};
            nv[t] = (vfloat4){0.f, 0.f, 0.f, 0.f};
        }
    }

    // ---- fast-path check: decide K==0 (margin ~2x) ----
    const float K6 = 0.2404491734814939f;        // log2(e)/6
    float mA = NEG, sA = 0.f;
    #pragma unroll
    for (int t = 0; t < 4; ++t) {
        mA = fmaxf(mA, fmaxf(fmaxf(lv[t][0], lv[t][1]), fmaxf(lv[t][2], lv[t][3])));
        sA += (fast_exp2(lv[t][0] * K6) + fast_exp2(lv[t][1] * K6))
            + (fast_exp2(lv[t][2] * K6) + fast_exp2(lv[t][3] * K6));
    }
    const float m1 = wave_max(mA);
    const float s1 = wave_sum(sA);
    const float mc = fast_exp2(m1 * K6) / s1;    // max softmax#1 prob
    const float sd = fmaf(0.6f, mc * mc, 0.3f);

    const float L2E = 1.4426950408889634f;
    float m2l = NEG, s2l = 0.f;
    #pragma unroll
    for (int t = 0; t < 4; ++t) {
        const float y0 = fmaf(nv[t][0], sd, lv[t][0] * (1.0f / 6.0f));
        const float y1 = fmaf(nv[t][1], sd, lv[t][1] * (1.0f / 6.0f));
        const float y2 = fmaf(nv[t][2], sd, lv[t][2] * (1.0f / 6.0f));
        const float y3 = fmaf(nv[t][3], sd, lv[t][3] * (1.0f / 6.0f));
        m2l = fmaxf(m2l, fmaxf(fmaxf(y0, y1), fmaxf(y2, y3)));
        s2l += (fast_exp2(y0 * L2E) + fast_exp2(y1 * L2E))
             + (fast_exp2(y2 * L2E) + fast_exp2(y3 * L2E));
    }
    const float m2  = wave_max(m2l);
    const float s2  = wave_sum(s2l);
    const float e2m = fast_exp2(m2 * L2E);       // overflow/NaN -> exact path

    // K==0 <=> max renorm prob <= 0.05; require maxp < 1/22 = 0.0455.
    // Data margin: maxp <= ~0.026. Fast path: no writes at all.
    if (__builtin_expect(!(s2 > 22.0f * e2m), 0)) {
        // ---- exact reference-semantics path (wave-uniform; cold) ----
        const float uu = u[row];
        const float m1x = m1 / 6.0f;             // max(l)/6 == max(l/6)
        float se1 = 0.f;
        #pragma unroll
        for (int t = 0; t < 4; ++t)
            se1 += expf(lv[t][0] / 6.0f - m1x) + expf(lv[t][1] / 6.0f - m1x)
                 + expf(lv[t][2] / 6.0f - m1x) + expf(lv[t][3] / 6.0f - m1x);
        const float s1x = wave_sum(se1);
        const float mcx = 1.0f / s1x;
        const float sdx = 0.3f + 0.6f * (mcx * mcx);

        float m2xl = NEG;
        #pragma unroll
        for (int t = 0; t < 4; ++t) {
            const float y0 = lv[t][0] / 6.0f + nv[t][0] * sdx;
            const float y1 = lv[t][1] / 6.0f + nv[t][1] * sdx;
            const float y2 = lv[t][2] / 6.0f + nv[t][2] * sdx;
            const float y3 = lv[t][3] / 6.0f + nv[t][3] * sdx;
            m2xl = fmaxf(m2xl, fmaxf(fmaxf(y0, y1), fmaxf(y2, y3)));
        }
        const float m2x = wave_max(m2xl);
        float se2 = 0.f;
        #pragma unroll
        for (int t = 0; t < 4; ++t)
            se2 += expf(lv[t][0] / 6.0f + nv[t][0] * sdx - m2x)
                 + expf(lv[t][1] / 6.0f + nv[t][1] * sdx - m2x)
                 + expf(lv[t][2] / 6.0f + nv[t][2] * sdx - m2x)
                 + expf(lv[t][3] / 6.0f + nv[t][3] * sdx - m2x);
        const float s2x = wave_sum(se2);
        float cs = 0.f;
        #pragma unroll
        for (int t = 0; t < 4; ++t)
            cs += fminf(expf(lv[t][0] / 6.0f + nv[t][0] * sdx - m2x) / s2x, 0.6f)
                + fminf(expf(lv[t][1] / 6.0f + nv[t][1] * sdx - m2x) / s2x, 0.6f)
                + fminf(expf(lv[t][2] / 6.0f + nv[t][2] * sdx - m2x) / s2x, 0.6f)
                + fminf(expf(lv[t][3] / 6.0f + nv[t][3] * sdx - m2x) / s2x, 0.6f);
        const float rsum = wave_sum(cs);
        int kls = 0;
        #pragma unroll
        for (int t = 0; t < 4; ++t) {
            const int j = lane + 64 * t;
            if (j < NF4) {
                const float yv[4] = {
                    lv[t][0] / 6.0f + nv[t][0] * sdx, lv[t][1] / 6.0f + nv[t][1] * sdx,
                    lv[t][2] / 6.0f + nv[t][2] * sdx, lv[t][3] / 6.0f + nv[t][3] * sdx };
                #pragma unroll
                for (int c = 0; c < 4; ++c) {
                    const float cl = fminf(expf(yv[c] - m2x) / s2x, 0.6f);
                    const int kk = (int)rintf((cl / rsum) * 10.0f);
                    kbuf[wid][4 * j + c] = (unsigned char)kk;
                    kls += kk;
                }
            }
        }
        const int K = wave_sumi(kls);
        int idx2;
        if (K == 0) {
            idx2 = count_below(uu * scan_val(1000));
        } else {
            asm volatile("s_waitcnt lgkmcnt(0)" ::: "memory");
            __builtin_amdgcn_wave_barrier();
            int cnt = 0;
            if (lane == 0) {
                const double tab[11] = {0.0, 0.1, 0.2, 0.3, 0.4, 0.5,
                                        0.6, 0.7, 0.8, 0.9, 1.0};
                double c = 0.0;
                for (int i = 0; i < NCLS; ++i) c += tab[kbuf[wid][i]];
                const double th = (double)uu * c;
                c = 0.0;
                for (int i = 0; i < NCLS; ++i) {
                    c += tab[kbuf[wid][i]];
                    cnt += (c < th) ? 1 : 0;
                }
            }
            idx2 = __shfl(cnt, 0);
        }
        // rewrite the row with the exact index
        const float V0 = logf(1e-7f);
        const float V1 = logf(0.9999f + 1e-7f);
        vfloat4* o4 = reinterpret_cast<vfloat4*>(out + (size_t)row * NCLS);
        #pragma unroll
        for (int t = 0; t < 4; ++t) {
            const int j = lane + 64 * t;
            if (j < NF4) {
                vfloat4 ov = {V0, V0, V0, V0};
                const int base = 4 * j;
                if (idx2 >= base && idx2 < base + 4)
                    ov[idx2 - base] = V1;
                o4[j] = ov;
            }
        }
    }
}

extern "C" void kernel_launch(void* const* d_in, const int* in_sizes, int n_in,
                              void* d_out, int out_size, void* d_ws, size_t ws_size,
                              hipStream_t stream) {
    const float* logits = (const float*)d_in[0];
    const float* noise  = (const float*)d_in[1];
    const float* u      = (const float*)d_in[2];
    float* out = (float*)d_out;

    const int batch = in_sizes[2];       // 32768 rows (u is [B,1])
    const int blocks = (batch + WPB - 1) / WPB;

    hipLaunchKernelGGL(writer_kernel, dim3(blocks), dim3(TPB), 0, stream,
                       u, out, batch);
    hipLaunchKernelGGL(verify_kernel, dim3(blocks), dim3(TPB), 0, stream,
                       logits, noise, u, out, batch);
}